// Round 9
// baseline (87.419 us; speedup 1.0000x reference)
//
#include <hip/hip_runtime.h>

typedef __attribute__((ext_vector_type(8))) _Float16 half8;
typedef __attribute__((ext_vector_type(4))) _Float16 half4;
typedef __attribute__((ext_vector_type(4))) float f32x4;
#if __has_builtin(__builtin_amdgcn_cvt_pkrtz)
typedef __attribute__((ext_vector_type(2))) __fp16 fp16x2;
#endif

#define ALPHA 0.2f
#define LOG2E 1.44269504f

__device__ __forceinline__ void gload_lds16(const void* g, void* l) {
  __builtin_amdgcn_global_load_lds((const __attribute__((address_space(1))) unsigned int*)g,
                                   (__attribute__((address_space(3))) unsigned int*)l, 16, 0, 0);
}

__device__ __forceinline__ float fexp2(float x) {
#if __has_builtin(__builtin_amdgcn_exp2f)
  return __builtin_amdgcn_exp2f(x);
#else
  return exp2f(x);
#endif
}

// ---------------- K0a: W fp32 -> fp16, PRE-SWIZZLED (unit8 XOR (n&7)) ----------------
__global__ __launch_bounds__(256) void k_convW(const float* __restrict__ W,
                                               _Float16* __restrict__ W16) {
  int idx4 = blockIdx.x * 256 + threadIdx.x;  // half4 unit
  int n = idx4 >> 7;                          // row 0..255
  int q = idx4 & 127;                         // half4 within row
  float4 v = *reinterpret_cast<const float4*>(W + n * 512 + q * 4);
  half4 hv = {(_Float16)v.x, (_Float16)v.y, (_Float16)v.z, (_Float16)v.w};
  int kp = (q * 4) ^ ((n & 7) << 3);          // swizzle within 64-elem blocks
  *reinterpret_cast<half4*>(W16 + n * 512 + kp) = hv;
}

// ---------------- K0b: u = W^T a  (8 blocks, coalesced over k) ----------------
__global__ __launch_bounds__(256) void k_uvec(const float* __restrict__ W,
                                              const float* __restrict__ a1,
                                              const float* __restrict__ a2,
                                              float* __restrict__ u1,
                                              float* __restrict__ u2) {
  __shared__ float p1[4][64], p2[4][64];
  int t = threadIdx.x;
  int l = t & 63, g = t >> 6;
  int k = blockIdx.x * 64 + l;
  float x1 = 0.f, x2 = 0.f;
  for (int o = g * 64; o < g * 64 + 64; ++o) {
    float wv = W[o * 512 + k];
    x1 += wv * a1[o];
    x2 += wv * a2[o];
  }
  p1[g][l] = x1; p2[g][l] = x2;
  __syncthreads();
  if (g == 0) {
    u1[k] = p1[0][l] + p1[1][l] + p1[2][l] + p1[3][l];
    u2[k] = p2[0][l] + p2[1][l] + p2[2][l] + p2[3][l];
  }
}

// ---------------- K2: Wh GEMM + fused s1/s2 (R2-proven structure, do not touch) ----------------
// block: 32 rows x 256 cols, 4 waves (each 32x64), 512 blocks (2/CU)
__global__ __launch_bounds__(256) void k_gemm_wh(const float* __restrict__ h,
                                                 const _Float16* __restrict__ W16,
                                                 const float* __restrict__ u1,
                                                 const float* __restrict__ u2,
                                                 float* __restrict__ s1o,
                                                 float* __restrict__ s2o,
                                                 _Float16* __restrict__ WhT) {
  __shared__ _Float16 Ab[2][32 * 64];    // 4 KB each, swizzled (reg-staged)
  __shared__ _Float16 Bb[2][256 * 64];   // 32 KB each, linear copy of pre-swizzled W16
  const int t = threadIdx.x, lane = t & 63, w = t >> 6;
  const int i0 = blockIdx.x * 32;        // global row 0..16383
  const int b = i0 >> 11, n0 = i0 & 2047;
  const int ar = t >> 3, au = t & 7;     // A-stage: row 0..31, 8-float chunk 0..7
  const float* hrow = h + (size_t)(i0 + ar) * 512 + au * 8;

  f32x4 acc[2][4];
#pragma unroll
  for (int mi = 0; mi < 2; ++mi)
#pragma unroll
    for (int ni = 0; ni < 4; ++ni) acc[mi][ni] = (f32x4){0.f, 0.f, 0.f, 0.f};

  // prologue: load A(0) regs, stage B(0) via global_load_lds
  float4 aR0 = *reinterpret_cast<const float4*>(hrow);
  float4 aR1 = *reinterpret_cast<const float4*>(hrow + 4);
#pragma unroll
  for (int q = 0; q < 8; ++q) {
    int idx = (q * 4 + w) * 64 + lane;
    int nn = idx >> 3, uu = idx & 7;
    gload_lds16(W16 + nn * 512 + uu * 8, (char*)&Bb[0][0] + idx * 16);
  }
  float x1 = 0.f, x2 = 0.f;

  for (int kt = 0; kt < 8; ++kt) {
    const int cur = kt & 1;
    // ds_write A(kt) (+ fused s1/s2 partials on the same registers)
    {
      half8 av;
      av[0] = (_Float16)aR0.x; av[1] = (_Float16)aR0.y;
      av[2] = (_Float16)aR0.z; av[3] = (_Float16)aR0.w;
      av[4] = (_Float16)aR1.x; av[5] = (_Float16)aR1.y;
      av[6] = (_Float16)aR1.z; av[7] = (_Float16)aR1.w;
      *reinterpret_cast<half8*>((char*)&Ab[cur][0] + ar * 128 + ((au * 16) ^ ((ar & 7) << 4))) = av;
      const float* up1 = u1 + kt * 64 + au * 8;
      const float* up2 = u2 + kt * 64 + au * 8;
      float4 u1a = *reinterpret_cast<const float4*>(up1);
      float4 u1b = *reinterpret_cast<const float4*>(up1 + 4);
      float4 u2a = *reinterpret_cast<const float4*>(up2);
      float4 u2b = *reinterpret_cast<const float4*>(up2 + 4);
      x1 += aR0.x * u1a.x + aR0.y * u1a.y + aR0.z * u1a.z + aR0.w * u1a.w
          + aR1.x * u1b.x + aR1.y * u1b.y + aR1.z * u1b.z + aR1.w * u1b.w;
      x2 += aR0.x * u2a.x + aR0.y * u2a.y + aR0.z * u2a.z + aR0.w * u2a.w
          + aR1.x * u2b.x + aR1.y * u2b.y + aR1.z * u2b.z + aR1.w * u2b.w;
    }
    __syncthreads();  // A(kt) visible; B(kt) loads drained
    if (kt < 7) {     // prefetch tile kt+1 (lands during compute below)
      const int k0 = (kt + 1) * 64;
      aR0 = *reinterpret_cast<const float4*>(hrow + k0);
      aR1 = *reinterpret_cast<const float4*>(hrow + k0 + 4);
#pragma unroll
      for (int q = 0; q < 8; ++q) {
        int idx = (q * 4 + w) * 64 + lane;
        int nn = idx >> 3, uu = idx & 7;
        gload_lds16(W16 + nn * 512 + k0 + uu * 8, (char*)&Bb[cur ^ 1][0] + idx * 16);
      }
    }
    // compute tile kt
    const char* Ac = (const char*)&Ab[cur][0];
    const char* Bc = (const char*)&Bb[cur][0];
#pragma unroll
    for (int kk = 0; kk < 2; ++kk) {
      const int jb = (lane >> 4) * 16 + kk * 64;
      half8 afr[2];
#pragma unroll
      for (int mi = 0; mi < 2; ++mi) {
        int rr = (lane & 15) + 16 * mi;
        afr[mi] = *reinterpret_cast<const half8*>(Ac + rr * 128 + (jb ^ ((rr & 7) << 4)));
      }
#pragma unroll
      for (int ni = 0; ni < 4; ++ni) {
        int nn = 64 * w + 16 * ni + (lane & 15);
        half8 bfr = *reinterpret_cast<const half8*>(Bc + nn * 128 + (jb ^ ((nn & 7) << 4)));
#pragma unroll
        for (int mi = 0; mi < 2; ++mi)
          acc[mi][ni] = __builtin_amdgcn_mfma_f32_16x16x32_f16(afr[mi], bfr, acc[mi][ni], 0, 0, 0);
      }
    }
  }
  // s1/s2: reduce over the 8 threads sharing a row (contiguous lanes)
  x1 += __shfl_xor(x1, 1); x1 += __shfl_xor(x1, 2); x1 += __shfl_xor(x1, 4);
  x2 += __shfl_xor(x2, 1); x2 += __shfl_xor(x2, 2); x2 += __shfl_xor(x2, 4);
  if (au == 0) { s1o[i0 + ar] = x1; s2o[i0 + ar] = x2; }
  // epilogue: pre-swizzled WhT store (unit8 XOR (c&7), within 64-n blocks)
  _Float16* whtb = WhT + (size_t)b * 256 * 2048;
#pragma unroll
  for (int mi = 0; mi < 2; ++mi)
#pragma unroll
    for (int ni = 0; ni < 4; ++ni) {
      int c = 64 * w + 16 * ni + (lane & 15);
      int nb = n0 + 16 * mi + (lane >> 4) * 4;
      int np = nb ^ ((c & 7) << 3);
      f32x4 a = acc[mi][ni];
      half4 hv = {(_Float16)a[0], (_Float16)a[1], (_Float16)a[2], (_Float16)a[3]};
      *reinterpret_cast<half4*>(whtb + (size_t)c * 2048 + np) = hv;
    }
}

#if __has_builtin(__builtin_amdgcn_cvt_pkrtz)
#define PACK2(DST, I, A, B)                        \
  { fp16x2 q_ = __builtin_amdgcn_cvt_pkrtz(A, B);  \
    DST[I] = (_Float16)q_[0]; DST[I + 1] = (_Float16)q_[1]; }
#else
#define PACK2(DST, I, A, B) { DST[I] = (_Float16)(A); DST[I + 1] = (_Float16)(B); }
#endif

// EXP8: one half8 A-fragment (8 consecutive j) for one row, + fp32 denom accumulation
#define EXP8(OUT, V0, V1, C1_, C2_, DS)                               \
  {                                                                   \
    float p0 = fexp2(fmaxf(C1_ + V0.x, fmaf(ALPHA, V0.x, C2_)));      \
    float p1 = fexp2(fmaxf(C1_ + V0.y, fmaf(ALPHA, V0.y, C2_)));      \
    float p2 = fexp2(fmaxf(C1_ + V0.z, fmaf(ALPHA, V0.z, C2_)));      \
    float p3 = fexp2(fmaxf(C1_ + V0.w, fmaf(ALPHA, V0.w, C2_)));      \
    float p4 = fexp2(fmaxf(C1_ + V1.x, fmaf(ALPHA, V1.x, C2_)));      \
    float p5 = fexp2(fmaxf(C1_ + V1.y, fmaf(ALPHA, V1.y, C2_)));      \
    float p6 = fexp2(fmaxf(C1_ + V1.z, fmaf(ALPHA, V1.z, C2_)));      \
    float p7 = fexp2(fmaxf(C1_ + V1.w, fmaf(ALPHA, V1.w, C2_)));      \
    DS += ((p0 + p1) + (p2 + p3)) + ((p4 + p5) + (p6 + p7));          \
    PACK2(OUT, 0, p0, p1); PACK2(OUT, 2, p2, p3);                     \
    PACK2(OUT, 4, p4, p5); PACK2(OUT, 6, p6, p7);                     \
  }

// ---------------- K3: fused softmax(P) @ Wh + ELU — register-P, m=2, LDS-minimal ----------------
// grid 256 (bid&7 = batch -> XCD affinity; bid>>3 = 64-row block), 512 thr = 8 waves
// (2 rg x 4 cg); wave = 32 rows x 64 cols via two 16-row A-fragments built IN REGISTERS
// (rank-1 P: 32 exps/lane/tile). B double-buffered 32 KB tiles staged by global_load_lds;
// counted vmcnt(4) keeps prefetch in flight across both per-tile barriers. P never
// touches LDS. Denominator: per-lane fp32 sums + shfl reduction (no ones-MFMA).
__global__ __launch_bounds__(512) void k_attn(const _Float16* __restrict__ WhT,
                                              const float* __restrict__ s1,
                                              const float* __restrict__ s2,
                                              float* __restrict__ out) {
  __shared__ _Float16 Bb[2][256 * 64];  // 32 KB each
  __shared__ float s2s[2048];           // log2e-scaled s2 for this batch
  __shared__ float red[8];
  const int t = threadIdx.x, lane = t & 63, w = t >> 6;
  const int rg = w >> 2, cg = w & 3;
  const int b = blockIdx.x & 7;
  const int i0 = (blockIdx.x >> 3) * 64;
  const _Float16* whtb = WhT + (size_t)b * 256 * 2048;
  const int arow = lane & 15;

  // stage s2 (scaled by log2e) + block-wide max; load this lane's two s1 rows
  float4 sv4 = *reinterpret_cast<const float4*>(s2 + b * 2048 + t * 4);
  float m0 = fmaxf(fmaxf(sv4.x, sv4.y), fmaxf(sv4.z, sv4.w));
  *reinterpret_cast<float4*>(&s2s[t * 4]) =
      make_float4(sv4.x * LOG2E, sv4.y * LOG2E, sv4.z * LOG2E, sv4.w * LOG2E);
#pragma unroll
  for (int off = 32; off >= 1; off >>= 1) m0 = fmaxf(m0, __shfl_xor(m0, off));
  if (lane == 0) red[w] = m0;
  const float s1A = s1[b * 2048 + i0 + rg * 32 + arow];
  const float s1B = s1[b * 2048 + i0 + rg * 32 + 16 + arow];
  __syncthreads();  // full drain: clean vmcnt slate; s2s/red visible
  float smaxL;
  {
    float mm = fmaxf(fmaxf(red[0], red[1]), fmaxf(red[2], red[3]));
    mm = fmaxf(mm, fmaxf(fmaxf(red[4], red[5]), fmaxf(red[6], red[7])));
    smaxL = mm * LOG2E;
  }
  // per-row softmax constants (closed-form row max; LeakyReLU monotonic)
  const float s1LA = LOG2E * s1A;
  const float eA = s1LA + smaxL;
  const float mA = fmaxf(eA, ALPHA * eA);
  const float C1A = s1LA - mA;
  const float C2A = fmaf(ALPHA, s1LA, -mA);
  const float s1LB = LOG2E * s1B;
  const float eB = s1LB + smaxL;
  const float mB = fmaxf(eB, ALPHA * eB);
  const float C1B = s1LB - mB;
  const float C2B = fmaf(ALPHA, s1LB, -mB);

  f32x4 acc[2][4];
#pragma unroll
  for (int mi = 0; mi < 2; ++mi)
#pragma unroll
    for (int ni = 0; ni < 4; ++ni) acc[mi][ni] = (f32x4){0.f, 0.f, 0.f, 0.f};
  float dsA = 0.f, dsB = 0.f;

  // issue B(0) -> buf0, B(1) -> buf1 (4 gload_lds16 per thread per tile)
#pragma unroll
  for (int x = 0; x < 2; ++x)
#pragma unroll
    for (int q = 0; q < 4; ++q) {
      int idx = q * 512 + t;
      int cl = idx >> 3, uu = idx & 7;
      gload_lds16(whtb + (size_t)cl * 2048 + x * 64 + uu * 8, (char*)&Bb[x][0] + idx * 16);
    }

  const int js = (lane >> 4) * 8;  // this lane's 8-j slice within a 32-j kk chunk
#pragma unroll 1
  for (int jt = 0; jt < 32; ++jt) {
    if (jt < 31) asm volatile("s_waitcnt vmcnt(4)" ::: "memory");
    else         asm volatile("s_waitcnt vmcnt(0)" ::: "memory");
    __builtin_amdgcn_s_barrier();  // B(jt) visible block-wide
    const char* Bc = (const char*)&Bb[jt & 1][0];
    // build 4 A-fragments in registers (rows A=rg*32+arow, B=+16; kk chunks 0,1)
    const float* sp = &s2s[jt * 64 + js];
    float4 v00 = *reinterpret_cast<const float4*>(sp);
    float4 v01 = *reinterpret_cast<const float4*>(sp + 4);
    float4 v10 = *reinterpret_cast<const float4*>(sp + 32);
    float4 v11 = *reinterpret_cast<const float4*>(sp + 36);
    half8 afrA0, afrA1, afrB0, afrB1;
    EXP8(afrA0, v00, v01, C1A, C2A, dsA);
    EXP8(afrA1, v10, v11, C1A, C2A, dsA);
    EXP8(afrB0, v00, v01, C1B, C2B, dsB);
    EXP8(afrB1, v10, v11, C1B, C2B, dsB);
    // MFMA: per kk, 4 B-reads feed 8 MFMAs (m=2)
#pragma unroll
    for (int kk = 0; kk < 2; ++kk) {
      const int jb = (lane >> 4) * 16 + kk * 64;  // byte offset of this lane's 8-j chunk
#pragma unroll
      for (int ni = 0; ni < 4; ++ni) {
        int cl = cg * 64 + 16 * ni + arow;
        half8 bfr = *reinterpret_cast<const half8*>(Bc + cl * 128 + (jb ^ ((cl & 7) << 4)));
        acc[0][ni] = __builtin_amdgcn_mfma_f32_16x16x32_f16(kk ? afrA1 : afrA0, bfr, acc[0][ni], 0, 0, 0);
        acc[1][ni] = __builtin_amdgcn_mfma_f32_16x16x32_f16(kk ? afrB1 : afrB0, bfr, acc[1][ni], 0, 0, 0);
      }
    }
    asm volatile("" ::: "memory");   // keep ds_reads above the barrier
    __builtin_amdgcn_s_barrier();    // all reads of buf[jt&1] done block-wide
    if (jt < 30) {  // refill the just-consumed buffer with B(jt+2)
      const int j0n = (jt + 2) * 64;
#pragma unroll
      for (int q = 0; q < 4; ++q) {
        int idx = q * 512 + t;
        int cl = idx >> 3, uu = idx & 7;
        gload_lds16(whtb + (size_t)cl * 2048 + j0n + uu * 8, (char*)&Bb[jt & 1][0] + idx * 16);
      }
    }
  }

  // denominators: lanes {r, r+16, r+32, r+48} hold disjoint j-chunks of rows (r, r+16)
  dsA += __shfl_xor(dsA, 16); dsA += __shfl_xor(dsA, 32);
  dsB += __shfl_xor(dsB, 16); dsB += __shfl_xor(dsB, 32);
  float invA[4], invB[4];
#pragma unroll
  for (int reg = 0; reg < 4; ++reg) {
    int rr = (lane >> 4) * 4 + reg;   // C/D row within 16-row tile
    invA[reg] = 1.0f / __shfl(dsA, rr);
    invB[reg] = 1.0f / __shfl(dsB, rr);
  }
  // epilogue: divide, ELU, store fp32
  const size_t ob = ((size_t)b * 2048 + i0 + rg * 32 + (lane >> 4) * 4) * 256 + cg * 64;
#pragma unroll
  for (int reg = 0; reg < 4; ++reg) {
#pragma unroll
    for (int ni = 0; ni < 4; ++ni) {
      int c = 16 * ni + arow;
      float v0 = acc[0][ni][reg] * invA[reg];
      v0 = v0 > 0.f ? v0 : (__expf(v0) - 1.f);
      out[ob + (size_t)reg * 256 + c] = v0;
      float v1 = acc[1][ni][reg] * invB[reg];
      v1 = v1 > 0.f ? v1 : (__expf(v1) - 1.f);
      out[ob + (size_t)(16 + reg) * 256 + c] = v1;
    }
  }
}

extern "C" void kernel_launch(void* const* d_in, const int* in_sizes, int n_in,
                              void* d_out, int out_size, void* d_ws, size_t ws_size,
                              hipStream_t stream) {
  (void)in_sizes; (void)n_in; (void)out_size; (void)ws_size;
  const float* h = (const float*)d_in[0];
  const float* W = (const float*)d_in[1];
  const float* a1 = (const float*)d_in[2];
  const float* a2 = (const float*)d_in[3];
  float* out = (float*)d_out;
  char* ws = (char*)d_ws;
  _Float16* WhT = (_Float16*)(ws);             // 8*256*2048*2 = 8388608 B (pre-swizzled)
  _Float16* W16 = (_Float16*)(ws + 8388608);   // 262144 B (pre-swizzled)
  float* u1 = (float*)(ws + 8650752);          // 2048 B
  float* u2 = (float*)(ws + 8652800);          // 2048 B
  float* s1 = (float*)(ws + 8654848);          // 65536 B
  float* s2 = (float*)(ws + 8720384);          // 65536 B

  hipLaunchKernelGGL(k_convW, dim3(128), dim3(256), 0, stream, W, W16);
  hipLaunchKernelGGL(k_uvec, dim3(8), dim3(256), 0, stream, W, a1, a2, u1, u2);
  hipLaunchKernelGGL(k_gemm_wh, dim3(512), dim3(256), 0, stream, h, W16, u1, u2, s1, s2, WhT);
  hipLaunchKernelGGL(k_attn, dim3(256), dim3(512), 0, stream, WhT, s1, s2, out);
}

// Round 10
// 67.073 us; speedup vs baseline: 1.3033x; 1.3033x over previous
//
#include <hip/hip_runtime.h>

typedef __attribute__((ext_vector_type(8))) _Float16 half8;
typedef __attribute__((ext_vector_type(4))) _Float16 half4;
typedef __attribute__((ext_vector_type(4))) float f32x4;
#if __has_builtin(__builtin_amdgcn_cvt_pkrtz)
typedef __attribute__((ext_vector_type(2))) __fp16 fp16x2;
#endif

#define ALPHA 0.2f
#define LOG2E 1.44269504f

__device__ __forceinline__ void gload_lds16(const void* g, void* l) {
  __builtin_amdgcn_global_load_lds((const __attribute__((address_space(1))) unsigned int*)g,
                                   (__attribute__((address_space(3))) unsigned int*)l, 16, 0, 0);
}

__device__ __forceinline__ float fexp2(float x) {
#if __has_builtin(__builtin_amdgcn_exp2f)
  return __builtin_amdgcn_exp2f(x);
#else
  return exp2f(x);
#endif
}

#if __has_builtin(__builtin_amdgcn_cvt_pkrtz)
#define PACK2(DST, I, A, B)                        \
  { fp16x2 q_ = __builtin_amdgcn_cvt_pkrtz(A, B);  \
    DST[I] = (_Float16)q_[0]; DST[I + 1] = (_Float16)q_[1]; }
#else
#define PACK2(DST, I, A, B) { DST[I] = (_Float16)(A); DST[I + 1] = (_Float16)(B); }
#endif

// EXP8: one half8 (8 consecutive j) of P for one row
#define EXP8(OUT, V0, V1, C1_, C2_)                                   \
  {                                                                   \
    float p0 = fexp2(fmaxf(C1_ + V0.x, fmaf(ALPHA, V0.x, C2_)));      \
    float p1 = fexp2(fmaxf(C1_ + V0.y, fmaf(ALPHA, V0.y, C2_)));      \
    float p2 = fexp2(fmaxf(C1_ + V0.z, fmaf(ALPHA, V0.z, C2_)));      \
    float p3 = fexp2(fmaxf(C1_ + V0.w, fmaf(ALPHA, V0.w, C2_)));      \
    float p4 = fexp2(fmaxf(C1_ + V1.x, fmaf(ALPHA, V1.x, C2_)));      \
    float p5 = fexp2(fmaxf(C1_ + V1.y, fmaf(ALPHA, V1.y, C2_)));      \
    float p6 = fexp2(fmaxf(C1_ + V1.z, fmaf(ALPHA, V1.z, C2_)));      \
    float p7 = fexp2(fmaxf(C1_ + V1.w, fmaf(ALPHA, V1.w, C2_)));      \
    PACK2(OUT, 0, p0, p1); PACK2(OUT, 2, p2, p3);                     \
    PACK2(OUT, 4, p4, p5); PACK2(OUT, 6, p6, p7);                     \
  }

// ---------------- K0: merged prologue — convW (blocks 0..127) + uvec (blocks 128..135) ----------------
__global__ __launch_bounds__(256) void k_prologue(const float* __restrict__ W,
                                                  const float* __restrict__ a1,
                                                  const float* __restrict__ a2,
                                                  _Float16* __restrict__ W16,
                                                  float* __restrict__ u1,
                                                  float* __restrict__ u2) {
  const int bid = blockIdx.x, t = threadIdx.x;
  if (bid < 128) {
    // W fp32 -> fp16, PRE-SWIZZLED (unit8 XOR (n&7))
    int idx4 = bid * 256 + t;
    int n = idx4 >> 7;
    int q = idx4 & 127;
    float4 v = *reinterpret_cast<const float4*>(W + n * 512 + q * 4);
    half4 hv = {(_Float16)v.x, (_Float16)v.y, (_Float16)v.z, (_Float16)v.w};
    int kp = (q * 4) ^ ((n & 7) << 3);
    *reinterpret_cast<half4*>(W16 + n * 512 + kp) = hv;
  } else {
    // u = W^T a (coalesced over k)
    __shared__ float p1[4][64], p2[4][64];
    int l = t & 63, g = t >> 6;
    int k = (bid - 128) * 64 + l;
    float x1 = 0.f, x2 = 0.f;
    for (int o = g * 64; o < g * 64 + 64; ++o) {
      float wv = W[o * 512 + k];
      x1 += wv * a1[o];
      x2 += wv * a2[o];
    }
    p1[g][l] = x1; p2[g][l] = x2;
    __syncthreads();
    if (g == 0) {
      u1[k] = p1[0][l] + p1[1][l] + p1[2][l] + p1[3][l];
      u2[k] = p2[0][l] + p2[1][l] + p2[2][l] + p2[3][l];
    }
  }
}

// ---------------- K2: Wh GEMM + fused s1/s2 (R2-proven structure, do not touch) ----------------
// block: 32 rows x 256 cols, 4 waves (each 32x64), 512 blocks (2/CU)
__global__ __launch_bounds__(256) void k_gemm_wh(const float* __restrict__ h,
                                                 const _Float16* __restrict__ W16,
                                                 const float* __restrict__ u1,
                                                 const float* __restrict__ u2,
                                                 float* __restrict__ s1o,
                                                 float* __restrict__ s2o,
                                                 _Float16* __restrict__ WhT) {
  __shared__ _Float16 Ab[2][32 * 64];    // 4 KB each, swizzled (reg-staged)
  __shared__ _Float16 Bb[2][256 * 64];   // 32 KB each, linear copy of pre-swizzled W16
  const int t = threadIdx.x, lane = t & 63, w = t >> 6;
  const int i0 = blockIdx.x * 32;        // global row 0..16383
  const int b = i0 >> 11, n0 = i0 & 2047;
  const int ar = t >> 3, au = t & 7;     // A-stage: row 0..31, 8-float chunk 0..7
  const float* hrow = h + (size_t)(i0 + ar) * 512 + au * 8;

  f32x4 acc[2][4];
#pragma unroll
  for (int mi = 0; mi < 2; ++mi)
#pragma unroll
    for (int ni = 0; ni < 4; ++ni) acc[mi][ni] = (f32x4){0.f, 0.f, 0.f, 0.f};

  // prologue: load A(0) regs, stage B(0) via global_load_lds
  float4 aR0 = *reinterpret_cast<const float4*>(hrow);
  float4 aR1 = *reinterpret_cast<const float4*>(hrow + 4);
#pragma unroll
  for (int q = 0; q < 8; ++q) {
    int idx = (q * 4 + w) * 64 + lane;
    int nn = idx >> 3, uu = idx & 7;
    gload_lds16(W16 + nn * 512 + uu * 8, (char*)&Bb[0][0] + idx * 16);
  }
  float x1 = 0.f, x2 = 0.f;

  for (int kt = 0; kt < 8; ++kt) {
    const int cur = kt & 1;
    // ds_write A(kt) (+ fused s1/s2 partials on the same registers)
    {
      half8 av;
      av[0] = (_Float16)aR0.x; av[1] = (_Float16)aR0.y;
      av[2] = (_Float16)aR0.z; av[3] = (_Float16)aR0.w;
      av[4] = (_Float16)aR1.x; av[5] = (_Float16)aR1.y;
      av[6] = (_Float16)aR1.z; av[7] = (_Float16)aR1.w;
      *reinterpret_cast<half8*>((char*)&Ab[cur][0] + ar * 128 + ((au * 16) ^ ((ar & 7) << 4))) = av;
      const float* up1 = u1 + kt * 64 + au * 8;
      const float* up2 = u2 + kt * 64 + au * 8;
      float4 u1a = *reinterpret_cast<const float4*>(up1);
      float4 u1b = *reinterpret_cast<const float4*>(up1 + 4);
      float4 u2a = *reinterpret_cast<const float4*>(up2);
      float4 u2b = *reinterpret_cast<const float4*>(up2 + 4);
      x1 += aR0.x * u1a.x + aR0.y * u1a.y + aR0.z * u1a.z + aR0.w * u1a.w
          + aR1.x * u1b.x + aR1.y * u1b.y + aR1.z * u1b.z + aR1.w * u1b.w;
      x2 += aR0.x * u2a.x + aR0.y * u2a.y + aR0.z * u2a.z + aR0.w * u2a.w
          + aR1.x * u2b.x + aR1.y * u2b.y + aR1.z * u2b.z + aR1.w * u2b.w;
    }
    __syncthreads();  // A(kt) visible; B(kt) loads drained
    if (kt < 7) {     // prefetch tile kt+1 (lands during compute below)
      const int k0 = (kt + 1) * 64;
      aR0 = *reinterpret_cast<const float4*>(hrow + k0);
      aR1 = *reinterpret_cast<const float4*>(hrow + k0 + 4);
#pragma unroll
      for (int q = 0; q < 8; ++q) {
        int idx = (q * 4 + w) * 64 + lane;
        int nn = idx >> 3, uu = idx & 7;
        gload_lds16(W16 + nn * 512 + k0 + uu * 8, (char*)&Bb[cur ^ 1][0] + idx * 16);
      }
    }
    // compute tile kt
    const char* Ac = (const char*)&Ab[cur][0];
    const char* Bc = (const char*)&Bb[cur][0];
#pragma unroll
    for (int kk = 0; kk < 2; ++kk) {
      const int jb = (lane >> 4) * 16 + kk * 64;
      half8 afr[2];
#pragma unroll
      for (int mi = 0; mi < 2; ++mi) {
        int rr = (lane & 15) + 16 * mi;
        afr[mi] = *reinterpret_cast<const half8*>(Ac + rr * 128 + (jb ^ ((rr & 7) << 4)));
      }
#pragma unroll
      for (int ni = 0; ni < 4; ++ni) {
        int nn = 64 * w + 16 * ni + (lane & 15);
        half8 bfr = *reinterpret_cast<const half8*>(Bc + nn * 128 + (jb ^ ((nn & 7) << 4)));
#pragma unroll
        for (int mi = 0; mi < 2; ++mi)
          acc[mi][ni] = __builtin_amdgcn_mfma_f32_16x16x32_f16(afr[mi], bfr, acc[mi][ni], 0, 0, 0);
      }
    }
  }
  // s1/s2: reduce over the 8 threads sharing a row (contiguous lanes)
  x1 += __shfl_xor(x1, 1); x1 += __shfl_xor(x1, 2); x1 += __shfl_xor(x1, 4);
  x2 += __shfl_xor(x2, 1); x2 += __shfl_xor(x2, 2); x2 += __shfl_xor(x2, 4);
  if (au == 0) { s1o[i0 + ar] = x1; s2o[i0 + ar] = x2; }
  // epilogue: pre-swizzled WhT store (unit8 XOR (c&7), within 64-n blocks)
  _Float16* whtb = WhT + (size_t)b * 256 * 2048;
#pragma unroll
  for (int mi = 0; mi < 2; ++mi)
#pragma unroll
    for (int ni = 0; ni < 4; ++ni) {
      int c = 64 * w + 16 * ni + (lane & 15);
      int nb = n0 + 16 * mi + (lane >> 4) * 4;
      int np = nb ^ ((c & 7) << 3);
      f32x4 a = acc[mi][ni];
      half4 hv = {(_Float16)a[0], (_Float16)a[1], (_Float16)a[2], (_Float16)a[3]};
      *reinterpret_cast<half4*>(whtb + (size_t)c * 2048 + np) = hv;
    }
}

// ---------------- K3: fused softmax(P) @ Wh + ELU — R8-proven structure, 2 blocks/CU ----------------
// grid 512 (bid&7 = batch -> XCD affinity; (bid>>3)&31 = 64-row block; bid>>8 = col half),
// 512 thr = 8 waves (4 rg x 2 cg), wave = 16 rows x 64 cols. Block covers 64 rows x 128 cols.
// B triple-buffered (16 KB tiles), P (64x64) double-buffered, s2 staged+scaled in LDS,
// per-batch max in-block. Counted vmcnt(2): loads span the single per-tile barrier (T3+T4).
__global__ __launch_bounds__(512) void k_attn(const _Float16* __restrict__ WhT,
                                              const float* __restrict__ s1,
                                              const float* __restrict__ s2,
                                              float* __restrict__ out) {
  __shared__ _Float16 Bb[3][128 * 64];  // 16 KB each
  __shared__ _Float16 Pb[2][64 * 64];   // 8 KB each
  __shared__ float s2s[2048];
  __shared__ float red[8];
  __shared__ float d_lds[64];
  const int t = threadIdx.x, lane = t & 63, w = t >> 6;
  const int rg = w >> 1, cg = w & 1;
  const int b = blockIdx.x & 7;
  const int i0 = ((blockIdx.x >> 3) & 31) * 64;
  const int ch = blockIdx.x >> 8;          // column half 0/1
  const _Float16* whtb = WhT + ((size_t)b * 256 + ch * 128) * 2048;
  const int arow = lane & 15;
  const int pr = t >> 3, pj8 = t & 7;      // P-build: row 0..63, 8-j chunk 0..7
  const float s1v = s1[b * 2048 + i0 + pr];

  // stage s2 (scaled by log2e) + block-wide max
  float4 sv4 = *reinterpret_cast<const float4*>(s2 + b * 2048 + t * 4);
  float m0 = fmaxf(fmaxf(sv4.x, sv4.y), fmaxf(sv4.z, sv4.w));
  *reinterpret_cast<float4*>(&s2s[t * 4]) =
      make_float4(sv4.x * LOG2E, sv4.y * LOG2E, sv4.z * LOG2E, sv4.w * LOG2E);
#pragma unroll
  for (int off = 32; off >= 1; off >>= 1) m0 = fmaxf(m0, __shfl_xor(m0, off));
  if (lane == 0) red[w] = m0;
  __syncthreads();  // full drain: clean vmcnt slate; s2s/red visible
  float smaxL;
  {
    float mm = fmaxf(fmaxf(red[0], red[1]), fmaxf(red[2], red[3]));
    mm = fmaxf(mm, fmaxf(fmaxf(red[4], red[5]), fmaxf(red[6], red[7])));
    smaxL = mm * LOG2E;
  }
  const float s1L = LOG2E * s1v;
  const float e0L = s1L + smaxL;
  const float mrowL = fmaxf(e0L, ALPHA * e0L);  // closed-form row max (LR monotonic)
  const float C1 = s1L - mrowL;
  const float C2 = fmaf(ALPHA, s1L, -mrowL);
  const int pwoff = pr * 128 + ((pj8 * 16) ^ ((pr & 7) << 4));
  half8 onesb;
  {
    _Float16 ov = (arow == 0) ? (_Float16)1.0f : (_Float16)0.0f;
#pragma unroll
    for (int x = 0; x < 8; ++x) onesb[x] = ov;
  }
  f32x4 acc[4];
#pragma unroll
  for (int ni = 0; ni < 4; ++ni) acc[ni] = (f32x4){0.f, 0.f, 0.f, 0.f};
  f32x4 accd = (f32x4){0.f, 0.f, 0.f, 0.f};

  // build P(0)
  {
    const float* sp = &s2s[pj8 * 8];
    float4 v0 = *reinterpret_cast<const float4*>(sp);
    float4 v1 = *reinterpret_cast<const float4*>(sp + 4);
    half8 ph;
    EXP8(ph, v0, v1, C1, C2);
    *reinterpret_cast<half8*>((char*)&Pb[0][0] + pwoff) = ph;
  }
  // issue B(0), B(1): 2 gload_lds per thread per tile (16 KB / 512 thr / 16 B)
#pragma unroll
  for (int x = 0; x < 2; ++x)
#pragma unroll
    for (int q = 0; q < 2; ++q) {
      int idx = q * 512 + t;
      int cl = idx >> 3, uu = idx & 7;
      gload_lds16(whtb + (size_t)cl * 2048 + x * 64 + uu * 8, (char*)&Bb[x][0] + idx * 16);
    }

  for (int jt = 0; jt < 32; ++jt) {
    // B(jt) landed (all but the 2 loads of B(jt+1)); own P ds_writes flushed pre-barrier
    if (jt < 31) asm volatile("s_waitcnt vmcnt(2) lgkmcnt(0)" ::: "memory");
    else         asm volatile("s_waitcnt vmcnt(0) lgkmcnt(0)" ::: "memory");
    __builtin_amdgcn_s_barrier();
    if (jt < 30) {  // issue B(jt+2) into slot (jt+2)%3 (safe: last reads were compute(jt-1))
      const int j0n = (jt + 2) * 64;
      const int p = (jt + 2) % 3;
#pragma unroll
      for (int q = 0; q < 2; ++q) {
        int idx = q * 512 + t;
        int cl = idx >> 3, uu = idx & 7;
        gload_lds16(whtb + (size_t)cl * 2048 + j0n + uu * 8, (char*)&Bb[p][0] + idx * 16);
      }
    }
    if (jt < 31) {  // build P(jt+1)
      const float* sp = &s2s[(jt + 1) * 64 + pj8 * 8];
      float4 v0 = *reinterpret_cast<const float4*>(sp);
      float4 v1 = *reinterpret_cast<const float4*>(sp + 4);
      half8 ph;
      EXP8(ph, v0, v1, C1, C2);
      *reinterpret_cast<half8*>((char*)&Pb[(jt + 1) & 1][0] + pwoff) = ph;
    }
    // compute tile jt
    const char* Bc = (const char*)&Bb[jt % 3][0];
    const char* Pc = (const char*)&Pb[jt & 1][0];
#pragma unroll
    for (int kk = 0; kk < 2; ++kk) {
      const int jb = ((lane >> 4) * 8 + kk * 32) * 2;
      const int ar64 = rg * 16 + arow;
      half8 afr = *reinterpret_cast<const half8*>(Pc + ar64 * 128 + (jb ^ ((ar64 & 7) << 4)));
      if (cg == 0)  // denominator: ones-column MFMA (row-sums of fp16 P)
        accd = __builtin_amdgcn_mfma_f32_16x16x32_f16(afr, onesb, accd, 0, 0, 0);
#pragma unroll
      for (int ni = 0; ni < 4; ++ni) {
        int cl = cg * 64 + 16 * ni + arow;
        half8 bfr = *reinterpret_cast<const half8*>(Bc + cl * 128 + (jb ^ ((cl & 7) << 4)));
        acc[ni] = __builtin_amdgcn_mfma_f32_16x16x32_f16(afr, bfr, acc[ni], 0, 0, 0);
      }
    }
  }
  // publish row denominators (col 0 of accd holds row-sums)
  if (cg == 0 && arow == 0) {
#pragma unroll
    for (int reg = 0; reg < 4; ++reg)
      d_lds[rg * 16 + (lane >> 4) * 4 + reg] = accd[reg];
  }
  __syncthreads();
  // epilogue: divide, ELU, store fp32
  const size_t ob = ((size_t)b * 2048 + i0 + rg * 16) * 256 + ch * 128 + cg * 64;
#pragma unroll
  for (int reg = 0; reg < 4; ++reg) {
    int rr = (lane >> 4) * 4 + reg;
    float inv = 1.0f / d_lds[rg * 16 + rr];
#pragma unroll
    for (int ni = 0; ni < 4; ++ni) {
      int c = 16 * ni + arow;
      float v = acc[ni][reg] * inv;
      v = v > 0.f ? v : (__expf(v) - 1.f);
      out[ob + (size_t)rr * 256 + c] = v;
    }
  }
}

extern "C" void kernel_launch(void* const* d_in, const int* in_sizes, int n_in,
                              void* d_out, int out_size, void* d_ws, size_t ws_size,
                              hipStream_t stream) {
  (void)in_sizes; (void)n_in; (void)out_size; (void)ws_size;
  const float* h = (const float*)d_in[0];
  const float* W = (const float*)d_in[1];
  const float* a1 = (const float*)d_in[2];
  const float* a2 = (const float*)d_in[3];
  float* out = (float*)d_out;
  char* ws = (char*)d_ws;
  _Float16* WhT = (_Float16*)(ws);             // 8*256*2048*2 = 8388608 B (pre-swizzled)
  _Float16* W16 = (_Float16*)(ws + 8388608);   // 262144 B (pre-swizzled)
  float* u1 = (float*)(ws + 8650752);          // 2048 B
  float* u2 = (float*)(ws + 8652800);          // 2048 B
  float* s1 = (float*)(ws + 8654848);          // 65536 B
  float* s2 = (float*)(ws + 8720384);          // 65536 B

  hipLaunchKernelGGL(k_prologue, dim3(136), dim3(256), 0, stream, W, a1, a2, W16, u1, u2);
  hipLaunchKernelGGL(k_gemm_wh, dim3(512), dim3(256), 0, stream, h, W16, u1, u2, s1, s2, WhT);
  hipLaunchKernelGGL(k_attn, dim3(512), dim3(512), 0, stream, WhT, s1, s2, out);
}